// Round 1
// baseline (1046.717 us; speedup 1.0000x reference)
//
#include <hip/hip_runtime.h>
#include <hip/hip_bf16.h>

// DF-HGNN fused pipeline, bf16 MFMA for all GEMMs, fp32 accumulation.
// N=20000 nodes, E=4096 edges, IN=512, DET=256, HID=256, HALF=128, OUT=2.

typedef __bf16 bf16_t;
typedef __attribute__((ext_vector_type(8))) __bf16 bf16x8;
typedef __attribute__((ext_vector_type(4))) __bf16 bf16x4;
typedef __attribute__((ext_vector_type(4))) float f32x4;

#define NN 20000
#define NE 4096
#define AT_S 16   // K-split factor for H^T @ Y

__device__ __forceinline__ f32x4 mfma16(bf16x8 a, bf16x8 b, f32x4 c) {
  return __builtin_amdgcn_mfma_f32_16x16x32_bf16(a, b, c, 0, 0, 0);
}

// ---------------------------------------------------------------- stats pass
// De[e] = sum_n H[n][e];  Dv[n] = sum_e H[n][e]*w[e]   (f32, atomically)
__global__ __launch_bounds__(256) void stats_kern(const float* __restrict__ H,
                                                  const float* __restrict__ w,
                                                  float* __restrict__ Dv,
                                                  float* __restrict__ De) {
  int l = threadIdx.x & 63, wv = threadIdx.x >> 6;
  int c = blockIdx.x * 256 + l * 4;            // 16 col-chunks of 256
  long rbase = (long)blockIdx.y * 160 + wv * 40;
  f32x4 w4 = *(const f32x4*)(w + c);
  f32x4 de; de[0] = de[1] = de[2] = de[3] = 0.f;
  for (int i = 0; i < 40; ++i) {
    long r = rbase + i;
    f32x4 v = *(const f32x4*)(H + r * NE + c);
    de += v;
    float s = v[0]*w4[0] + v[1]*w4[1] + v[2]*w4[2] + v[3]*w4[3];
    #pragma unroll
    for (int m = 1; m < 64; m <<= 1) s += __shfl_xor(s, m);
    if (l == 0) atomicAdd(&Dv[r], s);
  }
  #pragma unroll
  for (int j = 0; j < 4; ++j) atomicAdd(&De[c + j], de[j]);
}

__global__ void finalize_kern(const float* __restrict__ Dv, const float* __restrict__ De,
                              const float* __restrict__ w,
                              float* __restrict__ isd, float* __restrict__ es) {
  int t = blockIdx.x * 256 + threadIdx.x;
  if (t < NN) isd[t] = rsqrtf(fmaxf(Dv[t], 1e-6f));
  if (t < NE) es[t] = w[t] / fmaxf(De[t], 1e-6f);
}

// -------------------------------------------- weight transpose+cast (tiny)
// dst layouts are [out][in] bf16 so B-fragments are contiguous along K.
__global__ void cvtw_kern(const float* __restrict__ psi, const float* __restrict__ phi,
                          const float* __restrict__ g1,  const float* __restrict__ g2,
                          const float* __restrict__ th1, const float* __restrict__ th2,
                          bf16_t* dpsi, bf16_t* dphi, bf16_t* dg1, bf16_t* dg2,
                          bf16_t* dth1, bf16_t* dth2) {
  int t = blockIdx.x * 256 + threadIdx.x;
  if (t < 65536) {                       // psi [512][128] -> [128][512]
    int nc = t >> 9, k = t & 511; dpsi[t] = (__bf16)psi[k * 128 + nc];
  } else if (t < 98304) {                // phi [256][128] -> [128][256]
    int i = t - 65536; int nc = i >> 8, k = i & 255; dphi[i] = (__bf16)phi[k * 128 + nc];
  } else if (t < 163840) {               // g1 [256][256] -> [256][256]
    int i = t - 98304; int nc = i >> 8, k = i & 255; dg1[i] = (__bf16)g1[k * 256 + nc];
  } else if (t < 196608) {               // g2 [256][128] -> [128][256]
    int i = t - 163840; int nc = i >> 8, k = i & 255; dg2[i] = (__bf16)g2[k * 128 + nc];
  } else if (t < 229376) {               // th1 [128][256] -> [256][128]
    int i = t - 196608; int nc = i >> 7, k = i & 127; dth1[i] = (__bf16)th1[k * 256 + nc];
  } else if (t < 294912) {               // th2 [256][256] -> [256][256]
    int i = t - 229376; int nc = i >> 8, k = i & 255; dth2[i] = (__bf16)th2[k * 256 + nc];
  }
}

// --------------------------------------------------- node-feature GEMMs
// C[n][f] = A[n][:K] @ Bt[f][:K]^T, fused epilogues. Block: 64 rows x 128 cols,
// 4 waves (2x2), wave tile 32x64. LDS-free: both operands K-contiguous.
enum { EPI_CAT = 0, EPI_RELU = 1, EPI_GATE = 2, EPI_Y = 3 };

template<bool AF32, int EPI>
__global__ __launch_bounds__(256) void gemm_node_kern(
    const void* __restrict__ Av, int lda, const bf16_t* __restrict__ Bt, int K,
    const float* __restrict__ bias, float* __restrict__ gate_out,
    bf16_t* __restrict__ dst, int ldc, const bf16_t* __restrict__ cat,
    const float* __restrict__ isd) {
  int tid = threadIdx.x, l = tid & 63, wv = tid >> 6;
  int wr = wv >> 1, wc = wv & 1;
  int lr = l & 15, lq = l >> 4;
  int mo = blockIdx.x * 64 + wr * 32;
  int no = blockIdx.y * 128 + wc * 64;
  f32x4 acc[2][4] = {};
  for (int k0 = 0; k0 < K; k0 += 32) {
    bf16x8 a[2];
    #pragma unroll
    for (int mi = 0; mi < 2; ++mi) {
      int row = mo + mi * 16 + lr;
      bf16x8 t;
      if (row < NN) {
        if constexpr (AF32) {
          const float* ap = (const float*)Av + (long)row * lda + k0 + lq * 8;
          f32x4 u0 = *(const f32x4*)ap, u1 = *(const f32x4*)(ap + 4);
          #pragma unroll
          for (int j = 0; j < 4; ++j) { t[j] = (__bf16)u0[j]; t[j + 4] = (__bf16)u1[j]; }
        } else {
          t = *(const bf16x8*)((const bf16_t*)Av + (long)row * lda + k0 + lq * 8);
        }
      } else {
        #pragma unroll
        for (int j = 0; j < 8; ++j) t[j] = (__bf16)0.f;
      }
      a[mi] = t;
    }
    #pragma unroll
    for (int ni = 0; ni < 4; ++ni) {
      bf16x8 b = *(const bf16x8*)(Bt + (long)(no + ni * 16 + lr) * K + k0 + lq * 8);
      acc[0][ni] = mfma16(a[0], b, acc[0][ni]);
      acc[1][ni] = mfma16(a[1], b, acc[1][ni]);
    }
  }
  #pragma unroll
  for (int mi = 0; mi < 2; ++mi) {
    #pragma unroll
    for (int ni = 0; ni < 4; ++ni) {
      int colf = no + ni * 16 + lr;
      int rb = mo + mi * 16 + lq * 4;
      f32x4 v = acc[mi][ni];
      if constexpr (EPI == EPI_CAT) {
        float bs = bias[colf];
        for (int r = 0; r < 4; ++r) { int n = rb + r;
          if (n < NN) dst[(long)n * ldc + colf] = (__bf16)(v[r] + bs); }
      } else if constexpr (EPI == EPI_RELU) {
        float bs = bias[colf];
        for (int r = 0; r < 4; ++r) { int n = rb + r;
          if (n < NN) { float xx = v[r] + bs; dst[(long)n * ldc + colf] = (__bf16)(xx > 0.f ? xx : 0.f); } }
      } else if constexpr (EPI == EPI_GATE) {
        float bs = bias[colf];
        for (int r = 0; r < 4; ++r) {
          int n = rb + r;
          if (n < NN) {
            float g = 1.f / (1.f + __expf(-(v[r] + bs)));
            gate_out[(long)n * 128 + colf] = g;                  // gate -> d_out
            float px = (float)cat[(long)n * 256 + colf];
            float pz = (float)cat[(long)n * 256 + 128 + colf];
            dst[(long)n * 128 + colf] = (__bf16)(g * pz + (1.f - g) * px);  // fused
          }
        }
      } else {  // EPI_Y: Yt[f][n] = C * isd[n]  (transposed store, 8B packed)
        if (rb < NN) {
          bf16x4 pk;
          for (int r = 0; r < 4; ++r) pk[r] = (__bf16)(v[r] * isd[rb + r]);
          *(bf16x4*)(dst + (long)colf * NN + rb) = pk;
        }
      }
    }
  }
}

// --------------------------------------------- He partials: part[s][f][e]
// He[e][f] = sum_n H[n][e]*Yt[f][n]. Block: 128 e x 256 f, 4 waves split e,
// Yt tile [256][32] staged in LDS (pad 40). K=20000 split AT_S ways.
__global__ __launch_bounds__(256) void at_gemm_kern(const float* __restrict__ H,
                                                    const bf16_t* __restrict__ Yt,
                                                    bf16_t* __restrict__ part) {
  __shared__ bf16_t ly[256 * 40];
  int tid = threadIdx.x, l = tid & 63, wv = tid >> 6;
  int lr = l & 15, lq = l >> 4;
  int ew = blockIdx.x * 128 + wv * 32;
  int step0 = blockIdx.y * 40;
  int nsteps = min(40, 625 - step0);
  f32x4 acc[2][16] = {};
  for (int s = 0; s < nsteps; ++s) {
    int n0 = (step0 + s) * 32;
    __syncthreads();
    { const bf16x8* src = (const bf16x8*)(Yt + (long)tid * NN + n0);
      bf16_t* dr = ly + tid * 40;
      *(bf16x8*)(dr)      = src[0];
      *(bf16x8*)(dr + 8)  = src[1];
      *(bf16x8*)(dr + 16) = src[2];
      *(bf16x8*)(dr + 24) = src[3]; }
    __syncthreads();
    bf16x8 a[2];
    #pragma unroll
    for (int mi = 0; mi < 2; ++mi) {
      const float* hp = H + (long)(n0 + lq * 8) * NE + ew + mi * 16 + lr;
      bf16x8 t;
      #pragma unroll
      for (int j = 0; j < 8; ++j) t[j] = (__bf16)hp[(long)j * NE];
      a[mi] = t;
    }
    #pragma unroll
    for (int ni = 0; ni < 16; ++ni) {
      bf16x8 b = *(const bf16x8*)(ly + (ni * 16 + lr) * 40 + lq * 8);
      acc[0][ni] = mfma16(a[0], b, acc[0][ni]);
      acc[1][ni] = mfma16(a[1], b, acc[1][ni]);
    }
  }
  bf16_t* pp = part + (long)blockIdx.y * 256 * NE;
  #pragma unroll
  for (int mi = 0; mi < 2; ++mi)
    #pragma unroll
    for (int ni = 0; ni < 16; ++ni) {
      int f = ni * 16 + lr;
      int e = ew + mi * 16 + lq * 4;
      f32x4 v = acc[mi][ni];
      bf16x4 pk;
      for (int r = 0; r < 4; ++r) pk[r] = (__bf16)v[r];
      *(bf16x4*)(pp + (long)f * NE + e) = pk;
    }
}

// He_t[f][e] = es[e] * sum_s part[s][f][e]
__global__ void reduce_he(const bf16_t* __restrict__ part, const float* __restrict__ es,
                          bf16_t* __restrict__ Het) {
  int t = blockIdx.x * 256 + threadIdx.x;  // over 256*4096
  int e = t & (NE - 1);
  float s = 0.f;
  #pragma unroll
  for (int i = 0; i < AT_S; ++i) s += (float)part[(long)i * 256 * NE + t];
  Het[t] = (__bf16)(s * es[e]);
}

// ----------------------------- out = relu((H @ He)*isd + b) -> h[n][256]
// Computed transposed: C[f][n] = sum_e He_t[f][e]*H[n][e]. Block: 256 f x 64 n,
// 4 waves split n (16 each); He_t tile [256][32] staged in LDS.
__global__ __launch_bounds__(256) void out_gemm_kern(const bf16_t* __restrict__ Het,
                                                     const float* __restrict__ H,
                                                     const float* __restrict__ isd,
                                                     const float* __restrict__ bias,
                                                     bf16_t* __restrict__ h) {
  __shared__ bf16_t la[256 * 40];
  int tid = threadIdx.x, l = tid & 63, wv = tid >> 6;
  int lr = l & 15, lq = l >> 4;
  int n = blockIdx.x * 64 + wv * 16 + lr;
  bool nok = n < NN;
  f32x4 acc[16] = {};
  for (int e0 = 0; e0 < NE; e0 += 32) {
    __syncthreads();
    { const bf16x8* src = (const bf16x8*)(Het + (long)tid * NE + e0);
      bf16_t* dr = la + tid * 40;
      *(bf16x8*)(dr)      = src[0];
      *(bf16x8*)(dr + 8)  = src[1];
      *(bf16x8*)(dr + 16) = src[2];
      *(bf16x8*)(dr + 24) = src[3]; }
    __syncthreads();
    bf16x8 b;
    if (nok) {
      const float* hp = H + (long)n * NE + e0 + lq * 8;
      f32x4 u0 = *(const f32x4*)hp, u1 = *(const f32x4*)(hp + 4);
      #pragma unroll
      for (int j = 0; j < 4; ++j) { b[j] = (__bf16)u0[j]; b[j + 4] = (__bf16)u1[j]; }
    } else {
      #pragma unroll
      for (int j = 0; j < 8; ++j) b[j] = (__bf16)0.f;
    }
    #pragma unroll
    for (int mi = 0; mi < 16; ++mi) {
      bf16x8 a = *(const bf16x8*)(la + (mi * 16 + lr) * 40 + lq * 8);
      acc[mi] = mfma16(a, b, acc[mi]);
    }
  }
  if (!nok) return;
  float sd = isd[n];
  #pragma unroll
  for (int mi = 0; mi < 16; ++mi) {
    int fb = mi * 16 + lq * 4;
    f32x4 bs = *(const f32x4*)(bias + fb);
    bf16x4 pk;
    for (int r = 0; r < 4; ++r) {
      float v = acc[mi][r] * sd + bs[r];
      pk[r] = (__bf16)(v > 0.f ? v : 0.f);
    }
    *(bf16x4*)(h + (long)n * 256 + fb) = pk;   // h[n][f], 8B packed
  }
}

// ------------------------------------------- logits[n][2] = h[n]@out_w + b
__global__ __launch_bounds__(256) void logits_kern(const bf16_t* __restrict__ h,
                                                   const float* __restrict__ ow,
                                                   const float* __restrict__ ob,
                                                   float* __restrict__ out) {
  __shared__ float lw[512];
  int t = threadIdx.x;
  lw[t * 2] = ow[t * 2];
  lw[t * 2 + 1] = ow[t * 2 + 1];
  __syncthreads();
  int n = blockIdx.x * 256 + t;
  if (n >= NN) return;
  float a0 = ob[0], a1 = ob[1];
  const bf16x8* hp = (const bf16x8*)(h + (long)n * 256);
  for (int c = 0; c < 32; ++c) {
    bf16x8 v = hp[c];
    #pragma unroll
    for (int j = 0; j < 8; ++j) {
      float f = (float)v[j];
      a0 += f * lw[(c * 8 + j) * 2];
      a1 += f * lw[(c * 8 + j) * 2 + 1];
    }
  }
  out[n * 2] = a0;
  out[n * 2 + 1] = a1;
}

// ============================================================== launcher
extern "C" void kernel_launch(void* const* d_in, const int* in_sizes, int n_in,
                              void* d_out, int out_size, void* d_ws, size_t ws_size,
                              hipStream_t stream) {
  const float* x    = (const float*)d_in[0];
  const float* z    = (const float*)d_in[1];
  const float* H    = (const float*)d_in[2];
  const float* w    = (const float*)d_in[3];
  const float* psi_w = (const float*)d_in[4];
  const float* psi_b = (const float*)d_in[5];
  const float* phi_w = (const float*)d_in[6];
  const float* phi_b = (const float*)d_in[7];
  const float* g1_w  = (const float*)d_in[8];
  const float* g1_b  = (const float*)d_in[9];
  const float* g2_w  = (const float*)d_in[10];
  const float* g2_b  = (const float*)d_in[11];
  const float* th1   = (const float*)d_in[12];
  const float* b1    = (const float*)d_in[13];
  const float* th2   = (const float*)d_in[14];
  const float* b2    = (const float*)d_in[15];
  const float* out_w = (const float*)d_in[16];
  const float* out_b = (const float*)d_in[17];

  float* logits_out = (float*)d_out;            // [20000][2]
  float* gate_out   = logits_out + (size_t)NN * 2;  // [20000][128]

  char* p = (char*)d_ws;
  auto alloc = [&](size_t bytes) { char* r = p; p += (bytes + 255) & ~(size_t)255; return r; };
  float* Dv   = (float*)alloc((size_t)NN * 4);
  float* De   = (float*)alloc((size_t)NE * 4);
  float* isd  = (float*)alloc((size_t)NN * 4);
  float* es   = (float*)alloc((size_t)NE * 4);
  bf16_t* cat   = (bf16_t*)alloc((size_t)NN * 256 * 2);
  bf16_t* hid1  = (bf16_t*)alloc((size_t)NN * 256 * 2);
  bf16_t* fusedb= (bf16_t*)alloc((size_t)NN * 128 * 2);
  bf16_t* Yt    = (bf16_t*)alloc((size_t)256 * NN * 2);
  bf16_t* Het   = (bf16_t*)alloc((size_t)256 * NE * 2);
  bf16_t* h     = (bf16_t*)alloc((size_t)NN * 256 * 2);
  bf16_t* part  = (bf16_t*)alloc((size_t)AT_S * 256 * NE * 2);
  bf16_t* psi_wt = (bf16_t*)alloc(65536 * 2);
  bf16_t* phi_wt = (bf16_t*)alloc(32768 * 2);
  bf16_t* g1_wt  = (bf16_t*)alloc(65536 * 2);
  bf16_t* g2_wt  = (bf16_t*)alloc(32768 * 2);
  bf16_t* th1_wt = (bf16_t*)alloc(32768 * 2);
  bf16_t* th2_wt = (bf16_t*)alloc(65536 * 2);

  // zero the degree accumulators (Dv and De are adjacent allocations)
  hipMemsetAsync(Dv, 0, ((char*)isd - (char*)Dv), stream);

  cvtw_kern<<<1152, 256, 0, stream>>>(psi_w, phi_w, g1_w, g2_w, th1, th2,
                                      psi_wt, phi_wt, g1_wt, g2_wt, th1_wt, th2_wt);
  stats_kern<<<dim3(16, 125), 256, 0, stream>>>(H, w, Dv, De);
  finalize_kern<<<79, 256, 0, stream>>>(Dv, De, w, isd, es);

  // front-end MLP chain
  gemm_node_kern<true,  EPI_CAT ><<<dim3(313, 1), 256, 0, stream>>>(x, 512, psi_wt, 512, psi_b, nullptr, cat,       256, nullptr, nullptr);
  gemm_node_kern<true,  EPI_CAT ><<<dim3(313, 1), 256, 0, stream>>>(z, 256, phi_wt, 256, phi_b, nullptr, cat + 128, 256, nullptr, nullptr);
  gemm_node_kern<false, EPI_RELU><<<dim3(313, 2), 256, 0, stream>>>(cat, 256, g1_wt, 256, g1_b, nullptr, hid1, 256, nullptr, nullptr);
  gemm_node_kern<false, EPI_GATE><<<dim3(313, 1), 256, 0, stream>>>(hid1, 256, g2_wt, 256, g2_b, gate_out, fusedb, 128, cat, nullptr);

  // hconv 1
  gemm_node_kern<false, EPI_Y><<<dim3(313, 2), 256, 0, stream>>>(fusedb, 128, th1_wt, 128, nullptr, nullptr, Yt, 0, nullptr, isd);
  at_gemm_kern<<<dim3(32, AT_S), 256, 0, stream>>>(H, Yt, part);
  reduce_he<<<4096, 256, 0, stream>>>(part, es, Het);
  out_gemm_kern<<<313, 256, 0, stream>>>(Het, H, isd, b1, h);

  // hconv 2
  gemm_node_kern<false, EPI_Y><<<dim3(313, 2), 256, 0, stream>>>(h, 256, th2_wt, 256, nullptr, nullptr, Yt, 0, nullptr, isd);
  at_gemm_kern<<<dim3(32, AT_S), 256, 0, stream>>>(H, Yt, part);
  reduce_he<<<4096, 256, 0, stream>>>(part, es, Het);
  out_gemm_kern<<<313, 256, 0, stream>>>(Het, H, isd, b2, h);

  logits_kern<<<79, 256, 0, stream>>>(h, out_w, out_b, logits_out);
  (void)in_sizes; (void)n_in; (void)out_size; (void)ws_size;
}